// Round 1
// baseline (3627.146 us; speedup 1.0000x reference)
//
#include <hip/hip_runtime.h>
#include <math.h>

#define CIN_   512
#define COUT_  512
#define LATENT_ 512
#define NB_    8
#define HH_    64
#define WW_    64

#define TCI 4
#define TCO 16
#define XS_STRIDE 40   // padded from 34: wave's 4 rows land 8 banks apart -> 2-way (free)

// RC_W = 1/sqrt(9*512) ; RC_S = 1/sqrt(512) ; LRMUL = 1
__global__ __launch_bounds__(256) void style_kernel(
    const float* __restrict__ dlat, const float* __restrict__ mw,
    const float* __restrict__ mb, float* __restrict__ s)
{
    const float RC_S = 0.0441941738241592f;
    int n = blockIdx.x;
    int t = threadIdx.x;
    __shared__ float dl[LATENT_];
    for (int i = t; i < LATENT_; i += 256) dl[i] = dlat[n * LATENT_ + i];
    __syncthreads();
    for (int ci = t; ci < CIN_; ci += 256) {
        float acc = 0.f;
        for (int l = 0; l < LATENT_; ++l)
            acc += dl[l] * mw[l * CIN_ + ci];
        s[n * CIN_ + ci] = acc * RC_S + mb[ci] + 1.0f;
    }
}

__global__ __launch_bounds__(256) void wsq_kernel(
    const float* __restrict__ w, float* __restrict__ wsq)
{
    int idx = blockIdx.x * 256 + threadIdx.x;   // 0 .. 512*512-1  (= ci*512+co)
    float acc = 0.f;
#pragma unroll
    for (int tap = 0; tap < 9; ++tap) {
        float v = w[tap * (CIN_ * COUT_) + idx];
        acc += v * v;
    }
    wsq[idx] = acc;
}

__global__ __launch_bounds__(256) void demod_kernel(
    const float* __restrict__ s, const float* __restrict__ wsq,
    float* __restrict__ d)
{
    const float RCW2 = 1.0f / 4608.0f;   // RC_W^2
    int n = blockIdx.x;
    int t = threadIdx.x;
    __shared__ float s2[CIN_];
    for (int i = t; i < CIN_; i += 256) { float v = s[n * CIN_ + i]; s2[i] = v * v; }
    __syncthreads();
    for (int co = t; co < COUT_; co += 256) {
        float acc = 0.f;
        for (int ci = 0; ci < CIN_; ++ci)
            acc += s2[ci] * wsq[ci * COUT_ + co];
        d[n * COUT_ + co] = rsqrtf(RCW2 * acc + 1e-8f);
    }
}

// Output tile per block: one n, 16 co, 32x32 spatial.
// Threads: 16x16; each thread computes 2x2 spatial (spread by 16) x 16 co.
__global__ __launch_bounds__(256) void conv_kernel(
    const float* __restrict__ x, const float* __restrict__ w,
    const float* __restrict__ s, const float* __restrict__ d,
    float* __restrict__ out)
{
    const float RC_W = 0.0147313912747197f;  // 1/sqrt(4608)
    __shared__ __align__(16) float xs[TCI * 34 * XS_STRIDE];
    __shared__ __align__(16) float wt[9 * TCI * TCO];

    int b   = blockIdx.x;
    int bw  = b & 1;
    int bh  = (b >> 1) & 1;
    int bco = (b >> 2) & 31;
    int n   = b >> 7;

    int t  = threadIdx.x;
    int tx = t & 15;
    int ty = t >> 4;

    float acc[4][TCO];
#pragma unroll
    for (int i = 0; i < 4; ++i)
#pragma unroll
        for (int j = 0; j < TCO; ++j) acc[i][j] = 0.f;

    const int h_base = bh * 32, w_base = bw * 32;
    const float* xn = x + (size_t)n * CIN_ * HH_ * WW_;

    for (int cc = 0; cc < CIN_; cc += TCI) {
        // ---- stage x * s (with halo, zero-padded SAME borders) ----
        for (int idx = t; idx < TCI * 34 * 34; idx += 256) {
            int ci  = idx / (34 * 34);
            int rem = idx - ci * (34 * 34);
            int r   = rem / 34;
            int c   = rem - r * 34;
            int gh = h_base + r - 1;
            int gw = w_base + c - 1;
            float v = 0.f;
            if (gh >= 0 && gh < HH_ && gw >= 0 && gw < WW_)
                v = xn[(cc + ci) * (HH_ * WW_) + gh * WW_ + gw] * s[n * CIN_ + cc + ci];
            xs[ci * (34 * XS_STRIDE) + r * XS_STRIDE + c] = v;
        }
        // ---- stage weights * RC_W : wt[tap][ci][co] ----
        for (int idx = t; idx < 9 * TCI * TCO; idx += 256) {
            int tap = idx / (TCI * TCO);
            int rem = idx - tap * (TCI * TCO);
            int ci  = rem / TCO;
            int co  = rem - ci * TCO;
            wt[idx] = w[(tap * CIN_ + cc + ci) * COUT_ + bco * TCO + co] * RC_W;
        }
        __syncthreads();

        for (int ci = 0; ci < TCI; ++ci) {
            const float* xb = &xs[ci * (34 * XS_STRIDE)];
#pragma unroll
            for (int tap = 0; tap < 9; ++tap) {
                int kh = tap / 3;
                int kw = tap - 3 * kh;
                const float4* wp = (const float4*)&wt[(tap * TCI + ci) * TCO];
                float4 wa = wp[0], wb = wp[1], wc = wp[2], wd = wp[3];
#pragma unroll
                for (int rh = 0; rh < 2; ++rh) {
#pragma unroll
                    for (int rw = 0; rw < 2; ++rw) {
                        float xv = xb[(ty + 16 * rh + kh) * XS_STRIDE + tx + 16 * rw + kw];
                        int a = rh * 2 + rw;
                        acc[a][0]  += xv * wa.x;  acc[a][1]  += xv * wa.y;
                        acc[a][2]  += xv * wa.z;  acc[a][3]  += xv * wa.w;
                        acc[a][4]  += xv * wb.x;  acc[a][5]  += xv * wb.y;
                        acc[a][6]  += xv * wb.z;  acc[a][7]  += xv * wb.w;
                        acc[a][8]  += xv * wc.x;  acc[a][9]  += xv * wc.y;
                        acc[a][10] += xv * wc.z;  acc[a][11] += xv * wc.w;
                        acc[a][12] += xv * wd.x;  acc[a][13] += xv * wd.y;
                        acc[a][14] += xv * wd.z;  acc[a][15] += xv * wd.w;
                    }
                }
            }
        }
        __syncthreads();
    }

    // ---- epilogue: scale by demod, store ----
    float dv[TCO];
#pragma unroll
    for (int co = 0; co < TCO; ++co)
        dv[co] = d[n * COUT_ + bco * TCO + co];

#pragma unroll
    for (int co = 0; co < TCO; ++co) {
#pragma unroll
        for (int rh = 0; rh < 2; ++rh) {
#pragma unroll
            for (int rw = 0; rw < 2; ++rw) {
                int h = h_base + ty + 16 * rh;
                int ww_ = w_base + tx + 16 * rw;
                out[(((size_t)n * COUT_ + bco * TCO + co) * HH_ + h) * WW_ + ww_] =
                    acc[rh * 2 + rw][co] * dv[co];
            }
        }
    }
}

extern "C" void kernel_launch(void* const* d_in, const int* in_sizes, int n_in,
                              void* d_out, int out_size, void* d_ws, size_t ws_size,
                              hipStream_t stream) {
    const float* x    = (const float*)d_in[0];
    const float* dlat = (const float*)d_in[1];
    const float* w    = (const float*)d_in[2];
    const float* mw   = (const float*)d_in[3];
    const float* mb   = (const float*)d_in[4];
    float* out = (float*)d_out;

    float* s    = (float*)d_ws;                 // 8*512
    float* dmod = s + NB_ * CIN_;               // 8*512
    float* wsq  = dmod + NB_ * COUT_;           // 512*512

    style_kernel<<<NB_, 256, 0, stream>>>(dlat, mw, mb, s);
    wsq_kernel<<<(CIN_ * COUT_) / 256, 256, 0, stream>>>(w, wsq);
    demod_kernel<<<NB_, 256, 0, stream>>>(s, wsq, dmod);
    conv_kernel<<<NB_ * 32 * 2 * 2, 256, 0, stream>>>(x, w, s, dmod, out);
}

// Round 2
// 372.342 us; speedup vs baseline: 9.7414x; 9.7414x over previous
//
#include <hip/hip_runtime.h>
#include <math.h>

#define CIN_    512
#define COUT_   512
#define LATENT_ 512
#define NB_     8
#define HH_     64
#define WW_     64

typedef float f32x16 __attribute__((ext_vector_type(16)));
typedef short bf16x8v __attribute__((ext_vector_type(8)));

__device__ inline unsigned short f2bf(float f) {
    union { float f; unsigned u; } v; v.f = f;
    unsigned r = v.u + 0x7fffu + ((v.u >> 16) & 1u);
    return (unsigned short)(r >> 16);
}

// ---------------- style: s[n][ci] = dlat . (mw*RC_S) + mb + 1 ----------------
__global__ __launch_bounds__(256) void style_kernel(
    const float* __restrict__ dlat, const float* __restrict__ mw,
    const float* __restrict__ mb, float* __restrict__ s)
{
    const float RC_S = 0.0441941738241592f;
    int n = blockIdx.x;
    int t = threadIdx.x;
    __shared__ float dl[LATENT_];
    for (int i = t; i < LATENT_; i += 256) dl[i] = dlat[n * LATENT_ + i];
    __syncthreads();
    for (int ci = t; ci < CIN_; ci += 256) {
        float acc = 0.f;
        for (int l = 0; l < LATENT_; ++l)
            acc += dl[l] * mw[l * CIN_ + ci];
        s[n * CIN_ + ci] = acc * RC_S + mb[ci] + 1.0f;
    }
}

// ---------------- wsq[ci][co] = sum_tap w^2 (fp32, exact demod) --------------
__global__ __launch_bounds__(256) void wsq_kernel(
    const float* __restrict__ w, float* __restrict__ wsq)
{
    int idx = blockIdx.x * 256 + threadIdx.x;
    float acc = 0.f;
#pragma unroll
    for (int tap = 0; tap < 9; ++tap) {
        float v = w[tap * (CIN_ * COUT_) + idx];
        acc += v * v;
    }
    wsq[idx] = acc;
}

__global__ __launch_bounds__(256) void demod_kernel(
    const float* __restrict__ s, const float* __restrict__ wsq,
    float* __restrict__ d)
{
    const float RCW2 = 1.0f / 4608.0f;
    int n = blockIdx.x;
    int t = threadIdx.x;
    __shared__ float s2[CIN_];
    for (int i = t; i < CIN_; i += 256) { float v = s[n * CIN_ + i]; s2[i] = v * v; }
    __syncthreads();
    for (int co = t; co < COUT_; co += 256) {
        float acc = 0.f;
        for (int ci = 0; ci < CIN_; ++ci)
            acc += s2[ci] * wsq[ci * COUT_ + co];
        d[n * COUT_ + co] = rsqrtf(RCW2 * acc + 1e-8f);
    }
}

// ---- xt[n][cb][hp 66][wp 66][ci16] bf16 = x * s, zero-padded halo -----------
__global__ __launch_bounds__(256) void xprep_kernel(
    const float* __restrict__ x, const float* __restrict__ s,
    unsigned short* __restrict__ xt)
{
    int b = blockIdx.x;            // n*32*66 + cb*66 + hp
    int hp = b % 66;
    int cb = (b / 66) % 32;
    int n  = b / (66 * 32);
    int gh = hp - 1;
    unsigned short* dst = xt + (((size_t)(n * 32 + cb) * 66 + hp) * 66) * 16;
    for (int e = threadIdx.x; e < 66 * 16; e += 256) {
        int wp = e >> 4;
        int ci = e & 15;
        int gw = wp - 1;
        float v = 0.f;
        if (gh >= 0 && gh < HH_ && gw >= 0 && gw < WW_) {
            int c = cb * 16 + ci;
            v = x[(((size_t)n * CIN_ + c) * HH_ + gh) * WW_ + gw] * s[n * CIN_ + c];
        }
        dst[e] = f2bf(v);
    }
}

// ---- wb[tap][cb][co 512][ci16] bf16 = w[tap][ci][co] * RC_W  (transpose) ----
__global__ __launch_bounds__(256) void wprep_kernel(
    const float* __restrict__ w, unsigned short* __restrict__ wb)
{
    const float RC_W = 0.0147313912747197f;
    __shared__ float lt[16 * 521];
    int tap = blockIdx.x / 32;
    int cb  = blockIdx.x % 32;
    for (int idx = threadIdx.x; idx < 16 * 512; idx += 256) {
        int ci = idx >> 9;
        int co = idx & 511;
        lt[ci * 521 + co] = w[((size_t)tap * 512 + cb * 16 + ci) * 512 + co];
    }
    __syncthreads();
    unsigned short* dst = wb + (size_t)(tap * 32 + cb) * 512 * 16;
    for (int idx = threadIdx.x; idx < 16 * 512; idx += 256) {
        int co = idx >> 4;
        int ci = idx & 15;
        dst[idx] = f2bf(lt[ci * 521 + co] * RC_W);
    }
}

// ---------------- main conv: implicit GEMM on 32x32x16 bf16 MFMA -------------
// block: M=128 spatial (8 rows x 16 cols patch), N=128 co; 4 waves, each 64x64.
// K-loop: 32 chunks of 16 ci x 9 taps.
__global__ __launch_bounds__(256) void conv_mfma(
    const unsigned short* __restrict__ xt,
    const unsigned short* __restrict__ wb,
    const float* __restrict__ dmod,
    float* __restrict__ out)
{
    __shared__ __align__(16) union {
        struct { unsigned short xs[2880]; unsigned short ws[18432]; } s;  // 42624 B
        float o[64 * 129];                                                // 33024 B
    } sm;

    int b   = blockIdx.x;
    int cot = b & 3;
    int wt_ = (b >> 2) & 3;
    int ht  = (b >> 4) & 7;
    int n   = b >> 7;
    int h0 = ht * 8, w0 = wt_ * 16, co0 = cot * 128;

    int t    = threadIdx.x;
    int wv   = t >> 6, lane = t & 63;
    int mh   = wv >> 1, nh = wv & 1;
    int l5   = lane & 31, half = lane >> 5;

    f32x16 acc[2][2];
#pragma unroll
    for (int ms = 0; ms < 2; ++ms)
#pragma unroll
        for (int ns = 0; ns < 2; ++ns)
#pragma unroll
            for (int i = 0; i < 16; ++i) acc[ms][ns][i] = 0.f;

    for (int cb = 0; cb < 32; ++cb) {
        // stage x halo tile: 10 rows x 18 wp x 16 ci (360 x 16B)
        const unsigned short* xb = xt + (((size_t)(n * 32 + cb) * 66 + h0) * 66 + w0) * 16;
        for (int li = t; li < 360; li += 256) {
            int row = li / 36;
            int off = li - row * 36;
            *(uint4*)&sm.s.xs[row * 288 + off * 8] = *(const uint4*)&xb[row * 1056 + off * 8];
        }
        // stage weights: 9 taps x 128 co x 16 ci (each tap = 256 x 16B)
        const unsigned short* wbb = wb + ((size_t)cb * 512 + co0) * 16;
#pragma unroll
        for (int tap = 0; tap < 9; ++tap) {
            *(uint4*)&sm.s.ws[tap * 2048 + t * 8] =
                *(const uint4*)&wbb[(size_t)tap * 32 * 512 * 16 + t * 8];
        }
        __syncthreads();

#pragma unroll
        for (int tap = 0; tap < 9; ++tap) {
            int kh = tap / 3, kw = tap - 3 * (tap / 3);
            bf16x8v bfr[2], afr[2];
#pragma unroll
            for (int ns = 0; ns < 2; ++ns) {
                int co_l = nh * 64 + ns * 32 + l5;
                bfr[ns] = *(const bf16x8v*)&sm.s.ws[tap * 2048 + co_l * 16 + half * 8];
            }
#pragma unroll
            for (int ms = 0; ms < 2; ++ms) {
                int pr = mh * 4 + ms * 2 + (l5 >> 4);
                int pc = l5 & 15;
                int pos = (pr + kh) * 18 + (pc + kw);
                afr[ms] = *(const bf16x8v*)&sm.s.xs[pos * 16 + half * 8];
            }
#pragma unroll
            for (int ms = 0; ms < 2; ++ms)
#pragma unroll
                for (int ns = 0; ns < 2; ++ns)
                    acc[ms][ns] = __builtin_amdgcn_mfma_f32_32x32x16_bf16(
                        afr[ms], bfr[ns], acc[ms][ns], 0, 0, 0);
        }
        __syncthreads();
    }

    // epilogue: demod + LDS transpose + coalesced float4 stores (2 passes)
    for (int p = 0; p < 2; ++p) {
        __syncthreads();
        int co_l = nh * 64 + p * 32 + l5;
        int bco  = nh * 32 + l5;
        float dv = dmod[n * COUT_ + co0 + co_l];
#pragma unroll
        for (int ms = 0; ms < 2; ++ms) {
#pragma unroll
            for (int reg = 0; reg < 16; ++reg) {
                int ml = (reg & 3) + 8 * (reg >> 2) + 4 * half;
                int pr = mh * 4 + ms * 2 + (ml >> 4);
                int pc = ml & 15;
                sm.o[bco * 129 + pr * 16 + pc] = acc[ms][p][reg] * dv;
            }
        }
        __syncthreads();
        for (int j = t; j < 2048; j += 256) {
            int wq = j & 3;
            int pairidx = j >> 2;
            int row  = pairidx & 7;
            int bco2 = pairidx >> 3;
            int co = (bco2 >> 5) * 64 + p * 32 + (bco2 & 31);
            const float* src = &sm.o[bco2 * 129 + row * 16 + wq * 4];
            float4 v = make_float4(src[0], src[1], src[2], src[3]);
            *(float4*)&out[(((size_t)n * COUT_ + co0 + co) * HH_ + h0 + row) * WW_ + w0 + wq * 4] = v;
        }
    }
}

extern "C" void kernel_launch(void* const* d_in, const int* in_sizes, int n_in,
                              void* d_out, int out_size, void* d_ws, size_t ws_size,
                              hipStream_t stream) {
    const float* x    = (const float*)d_in[0];
    const float* dlat = (const float*)d_in[1];
    const float* w    = (const float*)d_in[2];
    const float* mw   = (const float*)d_in[3];
    const float* mb   = (const float*)d_in[4];
    float* out = (float*)d_out;

    char* ws = (char*)d_ws;
    float* s    = (float*)(ws);                       // 4096 f
    float* dmod = (float*)(ws + 16384);               // 4096 f
    float* wsq  = (float*)(ws + 32768);               // 262144 f
    unsigned short* xt = (unsigned short*)(ws + 1081344);    // 17,842,176 u16
    unsigned short* wb = (unsigned short*)(ws + 36765696);   // 2,359,296 u16

    style_kernel<<<NB_, 256, 0, stream>>>(dlat, mw, mb, s);
    wsq_kernel<<<(CIN_ * COUT_) / 256, 256, 0, stream>>>(w, wsq);
    demod_kernel<<<NB_, 256, 0, stream>>>(s, wsq, dmod);
    xprep_kernel<<<NB_ * 32 * 66, 256, 0, stream>>>(x, s, xt);
    wprep_kernel<<<9 * 32, 256, 0, stream>>>(w, wb);
    conv_mfma<<<1024, 256, 0, stream>>>(xt, wb, dmod, out);
}

// Round 3
// 329.901 us; speedup vs baseline: 10.9946x; 1.1286x over previous
//
#include <hip/hip_runtime.h>
#include <math.h>

#define CIN_    512
#define COUT_   512
#define LATENT_ 512
#define NB_     8
#define HH_     64
#define WW_     64

typedef float f32x16 __attribute__((ext_vector_type(16)));
typedef short bf16x8v __attribute__((ext_vector_type(8)));

__device__ inline unsigned short f2bf(float f) {
    union { float f; unsigned u; } v; v.f = f;
    unsigned r = v.u + 0x7fffu + ((v.u >> 16) & 1u);
    return (unsigned short)(r >> 16);
}

// ============ K1: fused wsq (blocks 0..1023) + wprep (1024..1311) + style (1312..1319)
// All three depend only on raw inputs.
__global__ __launch_bounds__(256) void prep1(
    const float* __restrict__ w, const float* __restrict__ dlat,
    const float* __restrict__ mw, const float* __restrict__ mb,
    float* __restrict__ wsq, unsigned short* __restrict__ wb,
    float* __restrict__ s)
{
    __shared__ float smem[16 * 521];   // wprep transpose buffer; style reuses [0..511]
    const float RC_W = 0.0147313912747197f;   // 1/sqrt(9*512)
    const float RC_S = 0.0441941738241592f;   // 1/sqrt(512)
    int b = blockIdx.x;
    int t = threadIdx.x;

    if (b < 1024) {
        // ---- wsq[ci][co] = sum_tap w^2 (fp32, exact demod) ----
        int idx = b * 256 + t;
        float acc = 0.f;
#pragma unroll
        for (int tap = 0; tap < 9; ++tap) {
            float v = w[tap * (CIN_ * COUT_) + idx];
            acc += v * v;
        }
        wsq[idx] = acc;
    } else if (b < 1312) {
        // ---- wprep: wb[tap][cb][co 512][ci16] = w[tap][ci][co]*RC_W (bf16, transposed)
        int bb  = b - 1024;
        int tap = bb / 32;
        int cb  = bb % 32;
        for (int idx = t; idx < 16 * 512; idx += 256) {
            int ci = idx >> 9;
            int co = idx & 511;
            smem[ci * 521 + co] = w[((size_t)tap * 512 + cb * 16 + ci) * 512 + co];
        }
        __syncthreads();
        unsigned short* dst = wb + (size_t)(tap * 32 + cb) * 512 * 16;
        for (int idx = t; idx < 16 * 512; idx += 256) {
            int co = idx >> 4;
            int ci = idx & 15;
            dst[idx] = f2bf(smem[ci * 521 + co] * RC_W);
        }
    } else {
        // ---- style: s[n][ci] = dlat . (mw*RC_S) + mb + 1 ----
        int n = b - 1312;
        for (int i = t; i < LATENT_; i += 256) smem[i] = dlat[n * LATENT_ + i];
        __syncthreads();
        for (int ci = t; ci < CIN_; ci += 256) {
            float acc = 0.f;
            for (int l = 0; l < LATENT_; ++l)
                acc += smem[l] * mw[l * CIN_ + ci];
            s[n * CIN_ + ci] = acc * RC_S + mb[ci] + 1.0f;
        }
    }
}

// ============ K2: fused demod (blocks 0..7) + xprep (8..16903)
// xprep: xt[n][cb][hp 66][wp 66][ci16] bf16 = x*s with zero-padded halo.
// Coalesced: stage 16ci x 64gw row-group via float4, LDS transpose (stride 67).
__global__ __launch_bounds__(256) void prep2(
    const float* __restrict__ x, const float* __restrict__ s,
    const float* __restrict__ wsq, float* __restrict__ dmod,
    unsigned short* __restrict__ xt)
{
    __shared__ float smem[16 * 67 + 16];   // 1088 floats; demod uses [0..511]
    int b = blockIdx.x;
    int t = threadIdx.x;

    if (b < 8) {
        // ---- demod: d[n][co] = rsqrt(RC_W^2 * sum_ci s^2 * wsq + 1e-8) ----
        const float RCW2 = 1.0f / 4608.0f;
        int n = b;
        for (int i = t; i < CIN_; i += 256) { float v = s[n * CIN_ + i]; smem[i] = v * v; }
        __syncthreads();
        for (int co = t; co < COUT_; co += 256) {
            float acc = 0.f;
            for (int ci = 0; ci < CIN_; ++ci)
                acc += smem[ci] * wsq[ci * COUT_ + co];
            dmod[n * COUT_ + co] = rsqrtf(RCW2 * acc + 1e-8f);
        }
    } else {
        int bb = b - 8;                  // n*32*66 + cb*66 + hp
        int hp = bb % 66;
        int cb = (bb / 66) % 32;
        int n  = bb / (66 * 32);
        int gh = hp - 1;
        bool rowok = (gh >= 0) && (gh < HH_);

        if (t < 16) smem[16 * 67 + t] = s[n * CIN_ + cb * 16 + t];
        if (rowok) {
            // 16 ci x 16 float4 = 256 threads, one float4 each (coalesced 256B/row)
            const float* src = &x[(((size_t)n * CIN_ + cb * 16) * HH_ + gh) * WW_];
            int ci = t >> 4;
            int g0 = (t & 15) * 4;
            float4 v = *(const float4*)&src[(size_t)ci * (HH_ * WW_) + g0];
            float* dstl = &smem[ci * 67 + g0];
            dstl[0] = v.x; dstl[1] = v.y; dstl[2] = v.z; dstl[3] = v.w;
        }
        __syncthreads();

        unsigned short* dst = xt + (((size_t)(n * 32 + cb) * 66 + hp) * 66) * 16;
        // 1056 u16 = 528 ushort2, coalesced
        for (int p = t; p < 528; p += 256) {
            int e  = p * 2;
            int wp = e >> 4;
            int ci = e & 15;
            int gw = wp - 1;
            float v0 = 0.f, v1 = 0.f;
            if (rowok && gw >= 0 && gw < WW_) {
                v0 = smem[ci * 67 + gw]       * smem[16 * 67 + ci];
                v1 = smem[(ci + 1) * 67 + gw] * smem[16 * 67 + ci + 1];
            }
            ushort2 o2; o2.x = f2bf(v0); o2.y = f2bf(v1);
            *(ushort2*)&dst[e] = o2;
        }
    }
}

// ============ main conv: implicit GEMM on 32x32x16 bf16 MFMA (unchanged, at plateau)
// block: M=128 spatial (8 rows x 16 cols patch), N=128 co; 4 waves, each 64x64.
__global__ __launch_bounds__(256) void conv_mfma(
    const unsigned short* __restrict__ xt,
    const unsigned short* __restrict__ wb,
    const float* __restrict__ dmod,
    float* __restrict__ out)
{
    __shared__ __align__(16) union {
        struct { unsigned short xs[2880]; unsigned short ws[18432]; } s;  // 42624 B
        float o[64 * 129];                                                // 33024 B
    } sm;

    int b   = blockIdx.x;
    int cot = b & 3;
    int wt_ = (b >> 2) & 3;
    int ht  = (b >> 4) & 7;
    int n   = b >> 7;
    int h0 = ht * 8, w0 = wt_ * 16, co0 = cot * 128;

    int t    = threadIdx.x;
    int wv   = t >> 6, lane = t & 63;
    int mh   = wv >> 1, nh = wv & 1;
    int l5   = lane & 31, half = lane >> 5;

    f32x16 acc[2][2];
#pragma unroll
    for (int ms = 0; ms < 2; ++ms)
#pragma unroll
        for (int ns = 0; ns < 2; ++ns)
#pragma unroll
            for (int i = 0; i < 16; ++i) acc[ms][ns][i] = 0.f;

    for (int cb = 0; cb < 32; ++cb) {
        // stage x halo tile: 10 rows x 18 wp x 16 ci (360 x 16B)
        const unsigned short* xb = xt + (((size_t)(n * 32 + cb) * 66 + h0) * 66 + w0) * 16;
        for (int li = t; li < 360; li += 256) {
            int row = li / 36;
            int off = li - row * 36;
            *(uint4*)&sm.s.xs[row * 288 + off * 8] = *(const uint4*)&xb[row * 1056 + off * 8];
        }
        // stage weights: 9 taps x 128 co x 16 ci (each tap = 256 x 16B)
        const unsigned short* wbb = wb + ((size_t)cb * 512 + co0) * 16;
#pragma unroll
        for (int tap = 0; tap < 9; ++tap) {
            *(uint4*)&sm.s.ws[tap * 2048 + t * 8] =
                *(const uint4*)&wbb[(size_t)tap * 32 * 512 * 16 + t * 8];
        }
        __syncthreads();

#pragma unroll
        for (int tap = 0; tap < 9; ++tap) {
            int kh = tap / 3, kw = tap - 3 * (tap / 3);
            bf16x8v bfr[2], afr[2];
#pragma unroll
            for (int ns = 0; ns < 2; ++ns) {
                int co_l = nh * 64 + ns * 32 + l5;
                bfr[ns] = *(const bf16x8v*)&sm.s.ws[tap * 2048 + co_l * 16 + half * 8];
            }
#pragma unroll
            for (int ms = 0; ms < 2; ++ms) {
                int pr = mh * 4 + ms * 2 + (l5 >> 4);
                int pc = l5 & 15;
                int pos = (pr + kh) * 18 + (pc + kw);
                afr[ms] = *(const bf16x8v*)&sm.s.xs[pos * 16 + half * 8];
            }
#pragma unroll
            for (int ms = 0; ms < 2; ++ms)
#pragma unroll
                for (int ns = 0; ns < 2; ++ns)
                    acc[ms][ns] = __builtin_amdgcn_mfma_f32_32x32x16_bf16(
                        afr[ms], bfr[ns], acc[ms][ns], 0, 0, 0);
        }
        __syncthreads();
    }

    // epilogue: demod + LDS transpose + coalesced float4 stores (2 passes)
    for (int p = 0; p < 2; ++p) {
        __syncthreads();
        int co_l = nh * 64 + p * 32 + l5;
        int bco  = nh * 32 + l5;
        float dv = dmod[n * COUT_ + co0 + co_l];
#pragma unroll
        for (int ms = 0; ms < 2; ++ms) {
#pragma unroll
            for (int reg = 0; reg < 16; ++reg) {
                int ml = (reg & 3) + 8 * (reg >> 2) + 4 * half;
                int pr = mh * 4 + ms * 2 + (ml >> 4);
                int pc = ml & 15;
                sm.o[bco * 129 + pr * 16 + pc] = acc[ms][p][reg] * dv;
            }
        }
        __syncthreads();
        for (int j = t; j < 2048; j += 256) {
            int wq = j & 3;
            int pairidx = j >> 2;
            int row  = pairidx & 7;
            int bco2 = pairidx >> 3;
            int co = (bco2 >> 5) * 64 + p * 32 + (bco2 & 31);
            const float* src = &sm.o[bco2 * 129 + row * 16 + wq * 4];
            float4 v = make_float4(src[0], src[1], src[2], src[3]);
            *(float4*)&out[(((size_t)n * COUT_ + co0 + co) * HH_ + h0 + row) * WW_ + w0 + wq * 4] = v;
        }
    }
}

extern "C" void kernel_launch(void* const* d_in, const int* in_sizes, int n_in,
                              void* d_out, int out_size, void* d_ws, size_t ws_size,
                              hipStream_t stream) {
    const float* x    = (const float*)d_in[0];
    const float* dlat = (const float*)d_in[1];
    const float* w    = (const float*)d_in[2];
    const float* mw   = (const float*)d_in[3];
    const float* mb   = (const float*)d_in[4];
    float* out = (float*)d_out;

    char* ws = (char*)d_ws;
    float* s    = (float*)(ws);                       // 4096 f
    float* dmod = (float*)(ws + 16384);               // 4096 f
    float* wsq  = (float*)(ws + 32768);               // 262144 f
    unsigned short* xt = (unsigned short*)(ws + 1081344);    // 17,842,176 u16
    unsigned short* wb = (unsigned short*)(ws + 36765696);   // 2,359,296 u16

    prep1<<<1320, 256, 0, stream>>>(w, dlat, mw, mb, wsq, wb, s);
    prep2<<<8 + NB_ * 32 * 66, 256, 0, stream>>>(x, s, wsq, dmod, xt);
    conv_mfma<<<1024, 256, 0, stream>>>(xt, wb, dmod, out);
}